// Round 3
// baseline (3145.071 us; speedup 1.0000x reference)
//
#include <hip/hip_runtime.h>
#include <hip/hip_bf16.h>

#define N_NODES 25000
#define N_EDGES 400000
#define S 64
#define V 32
#define L2C 16
#define TDIM 64
#define D 336          // S + 6V + 5*L2
#define FILMD 208

#define EPB 32         // edges per block
#define ES_STR 264     // es row stride in bf16
#define HID_STR 136    // hid row stride in bf16
#define W_STR 440      // w row stride in bf16 (432 used)

typedef short bf8 __attribute__((ext_vector_type(8)));
typedef float f4  __attribute__((ext_vector_type(4)));

__device__ __forceinline__ float silu_f(float x) { return x / (1.0f + __expf(-x)); }

__device__ __forceinline__ float wsum64(float x) {
    #pragma unroll
    for (int m = 32; m > 0; m >>= 1) x += __shfl_xor(x, m, 64);
    return x;
}
__device__ __forceinline__ float wsum32(float x) {
    #pragma unroll
    for (int m = 16; m > 0; m >>= 1) x += __shfl_xor(x, m, 32);
    return x;
}
__device__ __forceinline__ float wsum16(float x) {
    #pragma unroll
    for (int m = 8; m > 0; m >>= 1) x += __shfl_xor(x, m, 16);
    return x;
}

// ---------------- weight conversion (bf16, transposed) ----------------
__global__ __launch_bounds__(256) void convert_weights(
    const float* __restrict__ W1, const float* __restrict__ W2,
    __hip_bfloat16* __restrict__ Wb1t, __hip_bfloat16* __restrict__ Wb2t)
{
    const int i = blockIdx.x * 256 + threadIdx.x;
    if (i < 128 * 256) {
        const int n = i >> 8, k = i & 255;
        const float v = (k < 252) ? W1[k * 128 + n] : 0.0f;
        Wb1t[i] = __float2bfloat16(v);
    }
    if (i < 432 * 128) {
        const int n = i >> 7, k = i & 127;
        Wb2t[i] = __float2bfloat16(W2[k * 432 + n]);
    }
}

// ---------------- per-node projections hproj[n][48] = [h0@Wsv | h0@Wsl] ----------------
__global__ __launch_bounds__(256) void hproj_kernel(
    const float* __restrict__ h, const float* __restrict__ Wsv,
    const float* __restrict__ Wsl, float* __restrict__ hproj)
{
    const int idx = blockIdx.x * 256 + threadIdx.x;
    if (idx >= N_NODES * 48) return;
    const int n = idx / 48, o = idx - n * 48;
    const float* hr = h + (size_t)n * D;
    float a = 0.f;
    if (o < 32) {
        #pragma unroll 4
        for (int j = 0; j < 64; j++) a = fmaf(hr[j], Wsv[j * 32 + o], a);
    } else {
        const int c = o - 32;
        #pragma unroll 4
        for (int j = 0; j < 64; j++) a = fmaf(hr[j], Wsl[j * 16 + c], a);
    }
    hproj[idx] = a;
}

// ---------------- counting sort by dst ----------------
__global__ __launch_bounds__(256) void hist_kernel(const int* __restrict__ eidx, int* __restrict__ cnt) {
    const int e = blockIdx.x * 256 + threadIdx.x;
    if (e < N_EDGES) atomicAdd(&cnt[eidx[N_EDGES + e]], 1);
}

__global__ __launch_bounds__(1024) void scan_kernel(const int* __restrict__ cnt, int* __restrict__ offs) {
    __shared__ int part[1024];
    const int t = threadIdx.x;
    const int base = t * 25;               // 1024*25 = 25600 >= 25000
    int s = 0;
    for (int k = 0; k < 25; k++) {
        const int b = base + k;
        s += (b < N_NODES) ? cnt[b] : 0;
    }
    part[t] = s;
    __syncthreads();
    for (int off = 1; off < 1024; off <<= 1) {
        int v = (t >= off) ? part[t - off] : 0;
        __syncthreads();
        part[t] += v;
        __syncthreads();
    }
    int run = (t > 0) ? part[t - 1] : 0;
    for (int k = 0; k < 25; k++) {
        const int b = base + k;
        if (b < N_NODES) { offs[b] = run; run += cnt[b]; }
    }
    if (t == 1023) offs[N_NODES] = part[1023];
}

__global__ __launch_bounds__(256) void scatter_sort_kernel(
    const int* __restrict__ eidx, const int* __restrict__ offs,
    int* __restrict__ cur, int* __restrict__ sorted)
{
    const int e = blockIdx.x * 256 + threadIdx.x;
    if (e < N_EDGES) {
        const int d = eidx[N_EDGES + e];
        const int p = offs[d] + atomicAdd(&cur[d], 1);
        sorted[p] = e;
    }
}

// ---------------- main edge kernel: 32 sorted edges / block ----------------
__global__ __launch_bounds__(256, 4) void edge_kernel(
    const float* __restrict__ h, const float* __restrict__ coords,
    const int* __restrict__ eidx, const int* __restrict__ sorted,
    const int* __restrict__ etype, const int* __restrict__ ebt,
    const int* __restrict__ econj, const int* __restrict__ ering,
    const int* __restrict__ est, const float* __restrict__ eref,
    const float* __restrict__ t_emb,
    const float* __restrict__ type_emb, const float* __restrict__ bt_emb,
    const float* __restrict__ conj_emb, const float* __restrict__ ring_emb,
    const float* __restrict__ st_emb,
    const float* __restrict__ refW, const float* __restrict__ refb,
    const __hip_bfloat16* __restrict__ Wb1t, const float* __restrict__ b1,
    const __hip_bfloat16* __restrict__ Wb2t, const float* __restrict__ b2,
    const float* __restrict__ Wvs, const float* __restrict__ Wls,
    const float* __restrict__ Wlv, const float* __restrict__ Wvl,
    const float* __restrict__ hproj,
    float* __restrict__ agg)
{
    // LDS: uniA (es stride 264 overlaid by w stride 440) + hid + per-wave scratch = 40960 B
    __shared__ __hip_bfloat16 uniA[EPB * W_STR];   // 28160 B
    __shared__ __hip_bfloat16 hidA[EPB * HID_STR]; // 8704 B
    __shared__ float scratch[4][256];              // 4096 B: dv32|ql16|eci48|t112 160

    const int wid = threadIdx.x >> 6;
    const int l   = threadIdx.x & 63;
    const int spbase = blockIdx.x * EPB;

    const float R2 = 0.7071067811865476f;
    const float R6 = 0.4082482904638631f;

    // ---------------- Stage 1: edge features -> es (bf16) ----------------
    for (int i = 0; i < 8; i++) {
        const int le = wid * 8 + i;
        const int e  = __builtin_amdgcn_readfirstlane(sorted[spbase + le]);
        const int src = __builtin_amdgcn_readfirstlane(eidx[e]);
        const int dst = __builtin_amdgcn_readfirstlane(eidx[N_EDGES + e]);
        const float* cs = coords + 3 * src;
        const float* cd = coords + 3 * dst;
        const float dx = cd[0] - cs[0], dy = cd[1] - cs[1], dz = cd[2] - cs[2];
        const float dist = sqrtf(dx * dx + dy * dy + dz * dz + 1e-12f);
        __hip_bfloat16* es = uniA + le * ES_STR;
        es[60 + l]  = __float2bfloat16(h[(size_t)src * D + l]);
        es[124 + l] = __float2bfloat16(h[(size_t)dst * D + l]);
        es[188 + l] = __float2bfloat16(t_emb[(size_t)dst * TDIM + l]);
        const int et = etype[e];
        const int bt = ebt[e];
        const int ci = (bt >= 0) ? econj[e] : 2;
        const int ri = (bt >= 0) ? ering[e] : 2;
        const int si = est[e] + 1;
        const float er = eref[e];
        if (l < 16) {
            const float mu = (float)l * (5.0f / 15.0f);
            const float t = (dist - mu) * 3.0f;
            es[l] = __float2bfloat16(__expf(-t * t));
            es[16 + l] = __float2bfloat16(type_emb[et * 16 + l]);
        }
        if (l < 8) {
            es[32 + l] = __float2bfloat16(bt_emb[(bt + 1) * 8 + l]);
            const float ddv = dist - er;
            const float hr = (er > 0.f) ? 1.f : 0.f;
            es[52 + l] = __float2bfloat16(
                fabsf(ddv) * refW[l] + ddv * refW[8 + l] + hr * refW[16 + l] + refb[l]);
        }
        if (l < 4) {
            es[40 + l] = __float2bfloat16(conj_emb[ci * 4 + l]);
            es[44 + l] = __float2bfloat16(ring_emb[ri * 4 + l]);
            es[48 + l] = __float2bfloat16(st_emb[si * 4 + l]);
            es[252 + l] = __float2bfloat16(0.0f);  // K padding
        }
    }
    __syncthreads();

    // ---------------- Stage 2: GEMM1  hid[32x128] = silu(es @ W1 + b1) ----------------
    {
        const int q = l >> 4;
        const int t16 = l & 15;
        f4 acc[2][2];
        #pragma unroll
        for (int mt = 0; mt < 2; mt++)
            #pragma unroll
            for (int nt = 0; nt < 2; nt++) acc[mt][nt] = (f4){0.f, 0.f, 0.f, 0.f};
        const int n0 = wid * 32 + t16;
        #pragma unroll
        for (int kk = 0; kk < 256; kk += 32) {
            const int k0 = kk + q * 8;
            bf8 a[2];
            #pragma unroll
            for (int mt = 0; mt < 2; mt++)
                a[mt] = *(const bf8*)(uniA + (mt * 16 + t16) * ES_STR + k0);
            bf8 b[2];
            b[0] = *(const bf8*)(Wb1t + (size_t)n0 * 256 + k0);
            b[1] = *(const bf8*)(Wb1t + (size_t)(n0 + 16) * 256 + k0);
            #pragma unroll
            for (int mt = 0; mt < 2; mt++) {
                acc[mt][0] = __builtin_amdgcn_mfma_f32_16x16x32_bf16(a[mt], b[0], acc[mt][0], 0, 0, 0);
                acc[mt][1] = __builtin_amdgcn_mfma_f32_16x16x32_bf16(a[mt], b[1], acc[mt][1], 0, 0, 0);
            }
        }
        const float bias0 = b1[n0], bias1 = b1[n0 + 16];
        #pragma unroll
        for (int mt = 0; mt < 2; mt++) {
            #pragma unroll
            for (int r = 0; r < 4; r++) {
                const int m = mt * 16 + q * 4 + r;
                hidA[m * HID_STR + n0]      = __float2bfloat16(silu_f(acc[mt][0][r] + bias0));
                hidA[m * HID_STR + n0 + 16] = __float2bfloat16(silu_f(acc[mt][1][r] + bias1));
            }
        }
    }
    __syncthreads();

    // ---------------- Stage 3: GEMM2  w[32x432] = hid @ W2 + b2 ----------------
    {
        const int q = l >> 4;
        const int t16 = l & 15;
        bf8 a2[2][4];
        #pragma unroll
        for (int ks = 0; ks < 4; ks++) {
            const int k0 = ks * 32 + q * 8;
            #pragma unroll
            for (int mt = 0; mt < 2; mt++)
                a2[mt][ks] = *(const bf8*)(hidA + (mt * 16 + t16) * HID_STR + k0);
        }
        for (int t = wid; t < 27; t += 4) {
            const int n = t * 16 + t16;
            f4 acc[2];
            #pragma unroll
            for (int mt = 0; mt < 2; mt++) acc[mt] = (f4){0.f, 0.f, 0.f, 0.f};
            #pragma unroll
            for (int ks = 0; ks < 4; ks++) {
                const bf8 b = *(const bf8*)(Wb2t + (size_t)n * 128 + ks * 32 + q * 8);
                #pragma unroll
                for (int mt = 0; mt < 2; mt++)
                    acc[mt] = __builtin_amdgcn_mfma_f32_16x16x32_bf16(a2[mt][ks], b, acc[mt], 0, 0, 0);
            }
            const float bias = b2[n];
            #pragma unroll
            for (int mt = 0; mt < 2; mt++) {
                #pragma unroll
                for (int r = 0; r < 4; r++) {
                    const int m = mt * 16 + q * 4 + r;
                    uniA[m * W_STR + n] = __float2bfloat16(acc[mt][r] + bias);
                }
            }
        }
    }
    __syncthreads();

    // ---------------- Stage 4: message assembly, register accumulation per dst-run ----------------
    float* dv   = scratch[wid];
    float* ql   = dv + 32;
    float* eci  = ql + 16;
    float* t112 = eci + 48;

    float am0 = 0.f;
    float am1[6] = {0.f, 0.f, 0.f, 0.f, 0.f, 0.f};
    float am2[5] = {0.f, 0.f, 0.f, 0.f, 0.f};
    int cur_dst = -1;

    // prefetch registers
    int   p_src, p_dst;
    float p_h0, p_a0, p_a1, p_a2, p_b0, p_b1, p_b2;
    float p_c0, p_c1, p_c2, p_c3, p_c4, p_px;
    float p_cs0, p_cs1, p_cs2, p_cd0, p_cd1, p_cd2;

    auto loadE = [&](int i2, int& o_src, int& o_dst,
                     float& h0, float& a0, float& a1, float& a2,
                     float& b0, float& b1, float& b2,
                     float& c0, float& c1, float& c2, float& c3, float& c4,
                     float& px, float& cs0, float& cs1, float& cs2,
                     float& cd0, float& cd1, float& cd2) {
        const int le2 = wid * 8 + i2;
        const int e2  = __builtin_amdgcn_readfirstlane(sorted[spbase + le2]);
        o_src = __builtin_amdgcn_readfirstlane(eidx[e2]);
        o_dst = __builtin_amdgcn_readfirstlane(eidx[N_EDGES + e2]);
        const float* hr = h + (size_t)o_src * D;
        h0 = hr[l];
        if (l < 32) {
            a0 = hr[64 + 3 * l]; a1 = hr[65 + 3 * l]; a2 = hr[66 + 3 * l];
            b0 = hr[160 + 3 * l]; b1 = hr[161 + 3 * l]; b2 = hr[162 + 3 * l];
        }
        if (l < 16) {
            c0 = hr[256 + 5 * l]; c1 = hr[257 + 5 * l]; c2 = hr[258 + 5 * l];
            c3 = hr[259 + 5 * l]; c4 = hr[260 + 5 * l];
        }
        if (l >= 32)      px = hproj[(size_t)o_src * 48 + (l - 32)];
        else if (l >= 16) px = hproj[(size_t)o_src * 48 + 32 + (l - 16)];
        cs0 = coords[3 * o_src]; cs1 = coords[3 * o_src + 1]; cs2 = coords[3 * o_src + 2];
        cd0 = coords[3 * o_dst]; cd1 = coords[3 * o_dst + 1]; cd2 = coords[3 * o_dst + 2];
    };

    auto flush = [&]() {
        if (cur_dst >= 0) {
            float* ar = agg + (size_t)cur_dst * D;
            atomicAdd(ar + l, am0);
            am0 = 0.f;
            if (l < 32) {
                atomicAdd(ar + 64 + 3 * l + 0, am1[0]);
                atomicAdd(ar + 64 + 3 * l + 1, am1[1]);
                atomicAdd(ar + 64 + 3 * l + 2, am1[2]);
                atomicAdd(ar + 160 + 3 * l + 0, am1[3]);
                atomicAdd(ar + 160 + 3 * l + 1, am1[4]);
                atomicAdd(ar + 160 + 3 * l + 2, am1[5]);
                #pragma unroll
                for (int j = 0; j < 6; j++) am1[j] = 0.f;
            }
            if (l < 16) {
                #pragma unroll
                for (int k = 0; k < 5; k++) { atomicAdd(ar + 256 + 5 * l + k, am2[k]); am2[k] = 0.f; }
            }
        }
    };

    loadE(0, p_src, p_dst, p_h0, p_a0, p_a1, p_a2, p_b0, p_b1, p_b2,
          p_c0, p_c1, p_c2, p_c3, p_c4, p_px, p_cs0, p_cs1, p_cs2, p_cd0, p_cd1, p_cd2);

    for (int i = 0; i < 8; i++) {
        // current edge regs
        const int src = p_src, dst = p_dst;
        const float h0 = p_h0;
        const float a0 = p_a0, a1 = p_a1, a2 = p_a2;
        const float b0 = p_b0, b1 = p_b1, b2 = p_b2;
        const float c0 = p_c0, c1 = p_c1, c2 = p_c2, c3 = p_c3, c4 = p_c4;
        const float px = p_px;
        const float dx = p_cd0 - p_cs0, dy = p_cd1 - p_cs1, dz = p_cd2 - p_cs2;
        (void)src;

        if (i < 7)
            loadE(i + 1, p_src, p_dst, p_h0, p_a0, p_a1, p_a2, p_b0, p_b1, p_b2,
                  p_c0, p_c1, p_c2, p_c3, p_c4, p_px, p_cs0, p_cs1, p_cs2, p_cd0, p_cd1, p_cd2);

        if (dst != cur_dst) { flush(); cur_dst = dst; }

        const float dist = sqrtf(dx * dx + dy * dy + dz * dz + 1e-12f);
        const float inv = 1.0f / dist;
        const float ux = dx * inv, uy = dy * inv, uz = dz * inv;
        float y2a[5];
        y2a[0] = 2.f * R2 * ux * uy;
        y2a[1] = 2.f * R2 * ux * uz;
        y2a[2] = 2.f * R2 * uy * uz;
        y2a[3] = R2 * (ux * ux - uy * uy);
        y2a[4] = R6 * (ux * ux + uy * uy - 2.f * uz * uz);

        if (l < 32) {
            dv[l] = a0 * ux + a1 * uy + a2 * uz;
            t112[l * 5 + 0] = R2 * (a0 * uy + a1 * ux);
            t112[l * 5 + 1] = R2 * (a0 * uz + a2 * ux);
            t112[l * 5 + 2] = R2 * (a1 * uz + a2 * uy);
            t112[l * 5 + 3] = R2 * (a0 * ux - a1 * uy);
            t112[l * 5 + 4] = R6 * (a0 * ux + a1 * uy - 2.f * a2 * uz);
        }
        if (l < 16) {
            ql[l] = c0 * y2a[0] + c1 * y2a[1] + c2 * y2a[2] + c3 * y2a[3] + c4 * y2a[4];
            eci[l * 3 + 0] = R2 * (c0 * uy + c1 * uz + c3 * ux) + R6 * c4 * ux;
            eci[l * 3 + 1] = R2 * (c0 * ux + c2 * uz - c3 * uy) + R6 * c4 * uy;
            eci[l * 3 + 2] = R2 * (c1 * ux + c2 * uy) - 2.f * R6 * c4 * uz;
        }
        const float svv = __shfl(px, 32 + (l & 31), 64);  // hsv[src][v] for lanes <32
        const float slc = __shfl(px, 16 + (l & 15), 64);  // hsl[src][c] for lanes <16

        const int le = wid * 8 + i;
        const __hip_bfloat16* wrow = uniA + le * W_STR;

        // m0 (all lanes)
        {
            const float w00 = __bfloat162float(wrow[l]);
            const float w10 = __bfloat162float(wrow[64 + l]);
            const float w20 = __bfloat162float(wrow[128 + l]);
            float t1 = 0.f, t2 = 0.f;
            #pragma unroll
            for (int v = 0; v < 32; v++) t1 = fmaf(dv[v], Wvs[v * 64 + l], t1);
            #pragma unroll
            for (int c = 0; c < 16; c++) t2 = fmaf(ql[c], Wls[c * 64 + l], t2);
            am0 += w00 * h0 + w10 * t1 + w20 * t2;
        }

        // m1o / m1e (lanes < 32)
        if (l < 32) {
            const int v = l;
            const float w11o = __bfloat162float(wrow[192 + v]);
            const float w01o = __bfloat162float(wrow[224 + v]);
            const float wx1o = __bfloat162float(wrow[256 + v]);
            const float w21o = __bfloat162float(wrow[288 + v]);
            const float w11e = __bfloat162float(wrow[320 + v]);
            const float wx1e = __bfloat162float(wrow[352 + v]);
            const float co0 = b1 * uz - b2 * uy;
            const float co1 = b2 * ux - b0 * uz;
            const float co2 = b0 * uy - b1 * ux;
            const float ce0 = a1 * uz - a2 * uy;
            const float ce1 = a2 * ux - a0 * uz;
            const float ce2 = a0 * uy - a1 * ux;
            float t0 = 0.f, t1 = 0.f, t2 = 0.f;
            #pragma unroll
            for (int c = 0; c < 16; c++) {
                const float wl = Wlv[c * 32 + v];
                t0 = fmaf(eci[c * 3 + 0], wl, t0);
                t1 = fmaf(eci[c * 3 + 1], wl, t1);
                t2 = fmaf(eci[c * 3 + 2], wl, t2);
            }
            am1[0] += w11o * a0 + w01o * svv * ux + wx1o * co0 + w21o * t0;
            am1[1] += w11o * a1 + w01o * svv * uy + wx1o * co1 + w21o * t1;
            am1[2] += w11o * a2 + w01o * svv * uz + wx1o * co2 + w21o * t2;
            am1[3] += w11e * b0 + wx1e * ce0;
            am1[4] += w11e * b1 + wx1e * ce1;
            am1[5] += w11e * b2 + wx1e * ce2;
        }

        // m2 (lanes < 16)
        if (l < 16) {
            const int c = l;
            const float w22  = __bfloat162float(wrow[384 + c]);
            const float w112 = __bfloat162float(wrow[400 + c]);
            const float w02  = __bfloat162float(wrow[416 + c]);
            float tl0 = 0, tl1 = 0, tl2 = 0, tl3 = 0, tl4 = 0;
            #pragma unroll
            for (int v = 0; v < 32; v++) {
                const float wv = Wvl[v * 16 + c];
                tl0 = fmaf(t112[v * 5 + 0], wv, tl0);
                tl1 = fmaf(t112[v * 5 + 1], wv, tl1);
                tl2 = fmaf(t112[v * 5 + 2], wv, tl2);
                tl3 = fmaf(t112[v * 5 + 3], wv, tl3);
                tl4 = fmaf(t112[v * 5 + 4], wv, tl4);
            }
            am2[0] += w22 * c0 + w112 * tl0 + w02 * slc * y2a[0];
            am2[1] += w22 * c1 + w112 * tl1 + w02 * slc * y2a[1];
            am2[2] += w22 * c2 + w112 * tl2 + w02 * slc * y2a[2];
            am2[3] += w22 * c3 + w112 * tl3 + w02 * slc * y2a[3];
            am2[4] += w22 * c4 + w112 * tl4 + w02 * slc * y2a[4];
        }
    }
    flush();
}

// ---------------- node epilogue ----------------
__global__ __launch_bounds__(256) void node_kernel(
    const float* __restrict__ h, const float* __restrict__ t_emb,
    const float* __restrict__ agg,
    const float* __restrict__ P0, const float* __restrict__ P1o,
    const float* __restrict__ P1e, const float* __restrict__ P2,
    const float* __restrict__ filmW, const float* __restrict__ filmb,
    float* __restrict__ out)
{
    __shared__ float lds[4][336 + 64];
    const int wid = threadIdx.x >> 6;
    const int l = threadIdx.x & 63;
    const int n = blockIdx.x * 4 + wid;
    if (n >= N_NODES) return;
    float* ag = lds[wid];
    float* tv = ag + 336;
    const float* arow = agg + (size_t)n * D;
    const float* hrow = h + (size_t)n * D;
    for (int i = l; i < 336; i += 64) ag[i] = arow[i];
    tv[l] = t_emb[(size_t)n * TDIM + l];

    const int c2 = 128 + l;
    const int c3 = 192 + (l & 15);
    float f0 = filmb[l], f1 = filmb[64 + l], f2 = filmb[c2], f3 = filmb[c3];
    #pragma unroll 4
    for (int t = 0; t < 64; t++) {
        const float tt = tv[t];
        const float* fr = filmW + t * FILMD;
        f0 = fmaf(tt, fr[l], f0);
        f1 = fmaf(tt, fr[64 + l], f1);
        f2 = fmaf(tt, fr[c2], f2);
        f3 = fmaf(tt, fr[c3], f3);
    }

    {
        float a0 = 0.f;
        #pragma unroll 4
        for (int j = 0; j < 64; j++) a0 = fmaf(ag[j], P0[j * 64 + l], a0);
        a0 = silu_f(a0);
        const float hn0 = hrow[l] + a0;
        const float mu = wsum64(hn0) * (1.0f / 64.0f);
        const float d0 = hn0 - mu;
        const float var = wsum64(d0 * d0) * (1.0f / 64.0f);
        out[(size_t)n * D + l] = d0 * rsqrtf(var + 1e-6f) * (1.f + f0) + f1;
    }

    {
        const int v = l & 31;
        const bool iso = (l < 32);
        const float* Pm = iso ? P1o : P1e;
        const int base = iso ? 64 : 160;
        float a0 = 0.f, a1 = 0.f, a2 = 0.f;
        #pragma unroll 4
        for (int u = 0; u < 32; u++) {
            const float p = Pm[u * 32 + v];
            a0 = fmaf(ag[base + 3 * u + 0], p, a0);
            a1 = fmaf(ag[base + 3 * u + 1], p, a1);
            a2 = fmaf(ag[base + 3 * u + 2], p, a2);
        }
        const float x0 = hrow[base + 3 * v + 0] + a0;
        const float x1 = hrow[base + 3 * v + 1] + a1;
        const float x2 = hrow[base + 3 * v + 2] + a2;
        const float ssq = x0 * x0 + x1 * x1 + x2 * x2;
        const float s = wsum32(ssq);
        const float rinv = rsqrtf(s * (1.f / 32.f) + 1e-6f);
        const float sc = (1.f + f2) * rinv;
        out[(size_t)n * D + base + 3 * v + 0] = x0 * sc;
        out[(size_t)n * D + base + 3 * v + 1] = x1 * sc;
        out[(size_t)n * D + base + 3 * v + 2] = x2 * sc;
    }

    {
        const int c = l & 15;
        float xk[5];
        float ssq = 0.f;
        #pragma unroll
        for (int k = 0; k < 5; k++) {
            float a = 0.f;
            #pragma unroll
            for (int u = 0; u < 16; u++) a = fmaf(ag[256 + 5 * u + k], P2[u * 16 + c], a);
            const float x = hrow[256 + 5 * c + k] + a;
            xk[k] = x;
            ssq += x * x;
        }
        const float s = wsum16(ssq);
        const float rinv = rsqrtf(s * (1.f / 16.f) + 1e-6f);
        const float sc = (1.f + f3) * rinv;
        if (l < 16) {
            #pragma unroll
            for (int k = 0; k < 5; k++) out[(size_t)n * D + 256 + 5 * c + k] = xk[k] * sc;
        }
    }
}

extern "C" void kernel_launch(void* const* d_in, const int* in_sizes, int n_in,
                              void* d_out, int out_size, void* d_ws, size_t ws_size,
                              hipStream_t stream)
{
    const float* h        = (const float*)d_in[0];
    const float* coords   = (const float*)d_in[1];
    const int*   eidx     = (const int*)d_in[2];
    const int*   etype    = (const int*)d_in[3];
    const int*   ebt      = (const int*)d_in[4];
    const int*   econj    = (const int*)d_in[5];
    const int*   ering    = (const int*)d_in[6];
    const int*   est      = (const int*)d_in[7];
    const float* eref     = (const float*)d_in[8];
    const float* t_emb    = (const float*)d_in[9];
    const float* type_emb = (const float*)d_in[10];
    const float* bt_emb   = (const float*)d_in[11];
    const float* conj_emb = (const float*)d_in[12];
    const float* ring_emb = (const float*)d_in[13];
    const float* st_emb   = (const float*)d_in[14];
    const float* refW     = (const float*)d_in[15];
    const float* refb     = (const float*)d_in[16];
    const float* W1       = (const float*)d_in[17];
    const float* b1       = (const float*)d_in[18];
    const float* W2       = (const float*)d_in[19];
    const float* b2       = (const float*)d_in[20];
    const float* Wvs      = (const float*)d_in[21];
    const float* Wls      = (const float*)d_in[22];
    const float* Wsv      = (const float*)d_in[23];
    const float* Wlv      = (const float*)d_in[24];
    const float* Wvl      = (const float*)d_in[25];
    const float* Wsl      = (const float*)d_in[26];
    const float* P0       = (const float*)d_in[27];
    const float* P1o      = (const float*)d_in[28];
    const float* P1e      = (const float*)d_in[29];
    const float* P2       = (const float*)d_in[30];
    const float* filmW    = (const float*)d_in[31];
    const float* filmb    = (const float*)d_in[32];

    float* out = (float*)d_out;

    // workspace layout
    float* agg   = (float*)d_ws;                                  // 8.4M floats
    int*   cnt   = (int*)(agg + (size_t)N_NODES * D);             // 25000
    int*   cur   = cnt + N_NODES;                                 // 25000
    int*   offs  = cur + N_NODES;                                 // 25001
    int*   sorted = offs + N_NODES + 1;                           // 400000
    float* hproj = (float*)(sorted + N_EDGES);                    // 25000*48
    __hip_bfloat16* Wb1t = (__hip_bfloat16*)(hproj + (size_t)N_NODES * 48); // 128*256
    __hip_bfloat16* Wb2t = Wb1t + 128 * 256;                      // 432*128

    hipMemsetAsync(agg, 0, (size_t)N_NODES * D * sizeof(float), stream);
    hipMemsetAsync(cnt, 0, 2 * N_NODES * sizeof(int), stream);

    convert_weights<<<(432 * 128 + 255) / 256, 256, 0, stream>>>(W1, W2, Wb1t, Wb2t);
    hproj_kernel<<<(N_NODES * 48 + 255) / 256, 256, 0, stream>>>(h, Wsv, Wsl, hproj);
    hist_kernel<<<(N_EDGES + 255) / 256, 256, 0, stream>>>(eidx, cnt);
    scan_kernel<<<1, 1024, 0, stream>>>(cnt, offs);
    scatter_sort_kernel<<<(N_EDGES + 255) / 256, 256, 0, stream>>>(eidx, offs, cur, sorted);

    edge_kernel<<<N_EDGES / EPB, 256, 0, stream>>>(
        h, coords, eidx, sorted, etype, ebt, econj, ering, est, eref, t_emb,
        type_emb, bt_emb, conj_emb, ring_emb, st_emb, refW, refb,
        Wb1t, b1, Wb2t, b2, Wvs, Wls, Wlv, Wvl, hproj, agg);

    node_kernel<<<(N_NODES + 3) / 4, 256, 0, stream>>>(
        h, t_emb, agg, P0, P1o, P1e, P2, filmW, filmb, out);
}